// Round 9
// baseline (70.053 us; speedup 1.0000x reference)
//
#include <hip/hip_runtime.h>
#include <hip/hip_bf16.h>
#include <stdint.h>

#define B_ 4
#define K_ 2048
#define D_ 512
#define H_ 8
#define ATTN_ 128
#define M_ (B_ * K_)   // 8192

typedef __attribute__((ext_vector_type(4))) float f32x4;
typedef __attribute__((ext_vector_type(8))) short bf16x8;
typedef __attribute__((ext_vector_type(8))) unsigned short u16x8;
typedef __attribute__((ext_vector_type(2))) unsigned int u32x2;

__device__ __forceinline__ unsigned short f2bf(float f) {
    union { float f; unsigned int i; } x; x.f = f;
    unsigned int r = x.i + 0x7fffu + ((x.i >> 16) & 1u);   // RNE
    return (unsigned short)(r >> 16);
}
__device__ __forceinline__ float bf2f(unsigned short u) {
    union { unsigned int i; float f; } x; x.i = ((unsigned int)u) << 16; return x.f;
}
__device__ __forceinline__ void gload_lds16(const unsigned short* g, unsigned short* l) {
    __builtin_amdgcn_global_load_lds(
        (const __attribute__((address_space(1))) void*)g,
        (__attribute__((address_space(3))) void*)l, 16, 0, 0);
}
__device__ __forceinline__ unsigned lds_addr(const void* p) {
    return (unsigned)(unsigned long long)
        (const __attribute__((address_space(3))) void*)p;
}

// ---------------------------------------------------------------------------
// fp32 -> bf16 conversion: weights only (4 tensors)
// ---------------------------------------------------------------------------
struct Cvt { const float* s; unsigned short* d; int n8; };
struct CvtA { Cvt c[4]; };

__global__ __launch_bounds__(256)
void cvt_multi(CvtA a) {
    const Cvt c = a.c[blockIdx.y];
    const float4* s4 = (const float4*)c.s;
    u16x8* d8 = (u16x8*)c.d;
    for (int g = blockIdx.x * 256 + threadIdx.x; g < c.n8; g += gridDim.x * 256) {
        float4 f0 = s4[2 * g], f1 = s4[2 * g + 1];
        u16x8 o;
        o[0] = f2bf(f0.x); o[1] = f2bf(f0.y); o[2] = f2bf(f0.z); o[3] = f2bf(f0.w);
        o[4] = f2bf(f1.x); o[5] = f2bf(f1.y); o[6] = f2bf(f1.z); o[7] = f2bf(f1.w);
        d8[g] = o;
    }
}

// ---------------------------------------------------------------------------
// 256x256-tile GEMM, fused M across {q,k,v}: C_z[8192,512] = A_z @ W_z^T + b.
// BK=64 -> 8 K-tiles. 512 thr = 8 waves (2M x 4N), wave tile 128x64,
// acc[8][4] 16x16 frags (r2-validated layout & XOR swizzle, row stride 64).
// QKV grid = 192 blocks -> EVERY block co-resident, exactly one batch
// (r4-r8 lesson: per-step drain ~3-5k cyc is schedule-invariant; the lever
// is total steps x serial batches = 8 x 1 here vs 8 x 6 in r8).
// Each K-tile = 4 quadrant-phases (kk,nh): {ds_read frags; stage-issue per
// schedule; s_barrier; setprio 16 MFMA; s_barrier} -> wave-slip lets other
// waves' MFMA cover ds_read latency (T3-lite). Staging issued EARLY
// (A at p0, B at p1, A cvt+ds_write at p3), drained by the tile-boundary
// __syncthreads (proper compiler memory fence; raw s_barrier is NOT - LDS
// reads may hoist across it). Load-issue -> drain distance ~2-3 phases.
// ---------------------------------------------------------------------------
struct GArgs {
    const void* A[3];
    const unsigned short* Wt[3];
    const float* bias[3];
    void* C[3];
};

template<bool A_FP32, bool OUT_BF16>
__global__ __launch_bounds__(512)
void gemm256(GArgs args)
{
    __shared__ unsigned short As[2][256 * 64];   // 32 KB x2
    __shared__ unsigned short Bs[2][256 * 64];   // 32 KB x2 -> 128 KB total

    const int id  = blockIdx.x;
    const int cpx = gridDim.x >> 3;              // blocks per XCD (grid%8==0)
    const int swz = (id & 7) * cpx + (id >> 3);  // XCD-contiguous, bijective
    const int mt  = swz >> 1;                    // m-tile (256 rows), fused M
    const int nt  = swz & 1;
    const int z   = mt >> 5;                     // 32 m-tiles per z slice
    const int bm  = (mt & 31) * 256;
    const int bn  = nt * 256;

    const void* Az = args.A[z];
    const unsigned short* Wz = args.Wt[z];
    const float* biz = args.bias[z];
    void* Cz = args.C[z];

    const int tid = threadIdx.x;
    const int w   = tid >> 6;
    const int l   = tid & 63;
    const int lr  = l & 15;
    const int lhi = l >> 4;
    const int wm  = (w >> 2) * 128;              // wave_m 0..1
    const int wn  = (w & 3) * 64;                // wave_n 0..3

    f32x4 acc[8][4];
    #pragma unroll
    for (int m = 0; m < 8; ++m)
        #pragma unroll
        for (int n = 0; n < 4; ++n) acc[m][n] = (f32x4){0.f, 0.f, 0.f, 0.f};

    float4 fa[4][2];   // in-flight fp32 A tile (A_FP32 path), static-indexed

    auto loadA_f32 = [&](int t) {                // 8 float4 / thread
        #pragma unroll
        for (int q = 0; q < 4; ++q) {
            const int cid = q * 512 + tid;
            const int r = cid >> 3;
            const int c = (cid & 7) ^ (r & 7);   // load-side XOR permutation
            const float* src = (const float*)Az + (size_t)(bm + r) * D_ + t * 64 + c * 8;
            fa[q][0] = *(const float4*)src;
            fa[q][1] = *(const float4*)(src + 4);
        }
    };
    auto writeA_f32 = [&](int buf) {             // cvt + 4 ds_write_b128
        #pragma unroll
        for (int q = 0; q < 4; ++q) {
            const int cid = q * 512 + tid;
            u16x8 o;
            o[0] = f2bf(fa[q][0].x); o[1] = f2bf(fa[q][0].y);
            o[2] = f2bf(fa[q][0].z); o[3] = f2bf(fa[q][0].w);
            o[4] = f2bf(fa[q][1].x); o[5] = f2bf(fa[q][1].y);
            o[6] = f2bf(fa[q][1].z); o[7] = f2bf(fa[q][1].w);
            *(u16x8*)&As[buf][cid * 8] = o;      // linear dest: conflict-free
        }
    };
    auto stageA_b16 = [&](int buf, int t) {      // 4 gload_lds / thread
        #pragma unroll
        for (int q = 0; q < 4; ++q) {
            const int cid = q * 512 + tid;
            const int r = cid >> 3;
            const int c = (cid & 7) ^ (r & 7);
            gload_lds16((const unsigned short*)Az + (size_t)(bm + r) * D_ + t * 64 + c * 8,
                        &As[buf][(q * 512 + w * 64) * 8]);
        }
    };
    auto stageB = [&](int buf, int t) {          // 4 gload_lds / thread
        #pragma unroll
        for (int q = 0; q < 4; ++q) {
            const int cid = q * 512 + tid;
            const int r = cid >> 3;
            const int c = (cid & 7) ^ (r & 7);
            gload_lds16(Wz + (size_t)(bn + r) * D_ + t * 64 + c * 8,
                        &Bs[buf][(q * 512 + w * 64) * 8]);
        }
    };

    // Prologue: tile 0 staged, full drain.
    if (A_FP32) { loadA_f32(0); writeA_f32(0); }
    else        { stageA_b16(0, 0); }
    stageB(0, 0);
    __syncthreads();

    for (int t = 0; t < 8; ++t) {                // K = 512 = 8 x 64
        const int buf = t & 1;
        #pragma unroll
        for (int kk = 0; kk < 2; ++kk) {
            // A-frags for this K-half (reused across both nh phases)
            bf16x8 af[8];
            #pragma unroll
            for (int m = 0; m < 8; ++m) {
                const int row = wm + m * 16 + lr;
                const int sl  = (kk * 4 + lhi) ^ (row & 7);
                af[m] = *(const bf16x8*)&As[buf][row * 64 + sl * 8];
            }
            #pragma unroll
            for (int nh = 0; nh < 2; ++nh) {
                bf16x8 bfr[2];
                #pragma unroll
                for (int n2 = 0; n2 < 2; ++n2) {
                    const int row = wn + (nh * 2 + n2) * 16 + lr;
                    const int sl  = (kk * 4 + lhi) ^ (row & 7);
                    bfr[n2] = *(const bf16x8*)&Bs[buf][row * 64 + sl * 8];
                }
                const int p = kk * 2 + nh;       // phase 0..3
                if (t < 7) {                     // stage tile t+1 (early issue)
                    if (p == 0) {
                        if (A_FP32) loadA_f32(t + 1);
                        else        stageA_b16(buf ^ 1, t + 1);
                    } else if (p == 1) {
                        stageB(buf ^ 1, t + 1);
                    } else if (p == 3 && A_FP32) {
                        writeA_f32(buf ^ 1);     // compiler waits fa (3-phase cover)
                    }
                }
                __builtin_amdgcn_s_barrier();    // pace waves into MFMA
                __builtin_amdgcn_s_setprio(1);
                #pragma unroll
                for (int m = 0; m < 8; ++m)
                    #pragma unroll
                    for (int n2 = 0; n2 < 2; ++n2)
                        acc[m][nh * 2 + n2] = __builtin_amdgcn_mfma_f32_16x16x32_bf16(
                            af[m], bfr[n2], acc[m][nh * 2 + n2], 0, 0, 0);
                __builtin_amdgcn_s_setprio(0);
                if (p < 3) __builtin_amdgcn_s_barrier();
            }
        }
        // Tile boundary: true fence + drain (loads were issued >=2 phases ago)
        __syncthreads();
    }

    float bv[4];
    #pragma unroll
    for (int fn = 0; fn < 4; ++fn) bv[fn] = biz[bn + wn + fn * 16 + lr];

    #pragma unroll
    for (int m = 0; m < 8; ++m)
        #pragma unroll
        for (int fn = 0; fn < 4; ++fn)
            #pragma unroll
            for (int rr = 0; rr < 4; ++rr) {
                const int row = bm + wm + m * 16 + lhi * 4 + rr;
                const int col = bn + wn + fn * 16 + lr;
                const float val = acc[m][fn][rr] + bv[fn];
                if (OUT_BF16)
                    ((unsigned short*)Cz)[(size_t)row * 512 + col] = f2bf(val);
                else
                    ((float*)Cz)[(size_t)row * 512 + col] = val;
            }
}

// ---------------------------------------------------------------------------
// MFMA banded-causal local attention (round-3 validated, unchanged).
// ---------------------------------------------------------------------------
__global__ __launch_bounds__(256)
void attn_mfma(const unsigned short* __restrict__ qb,
               const unsigned short* __restrict__ kb,
               const unsigned short* __restrict__ vb,
               unsigned short* __restrict__ ob)
{
    __shared__ unsigned short Ksh[192 * 64];
    __shared__ unsigned short Vsh[4 * 192 * 16];
    __shared__ unsigned short Psh[4 * 16 * 200];

    const int flat = blockIdx.x + 32 * (blockIdx.y + 8 * blockIdx.z);
    const int lg   = (flat & 7) * 128 + (flat >> 3);
    const int tile = lg & 31;
    const int h    = (lg >> 5) & 7;
    const int b    = lg >> 8;

    const int i0 = tile * 64;
    const int j0 = i0 - 128;
    const int tid = threadIdx.x;
    const int w   = tid >> 6;
    const int l   = tid & 63;
    const int lr  = l & 15;
    const int lhi = l >> 4;
    const float scale = 0.0220970869120796f;

    const size_t hbase = ((size_t)b * K_) * 512 + (size_t)h * 64;
    const unsigned short* kh = kb + hbase;
    const unsigned short* vh = vb + hbase;
    const unsigned short* qh = qb + hbase;
    unsigned short* oh = ob + hbase;

    #pragma unroll
    for (int it = 0; it < 6; ++it) {
        const int cg  = it * 4 + w;
        const int cid = cg * 64 + l;
        const int r = cid >> 3, c = cid & 7;
        const int cs = c ^ (r & 7);
        int j = j0 + r; if (j < 0) j = 0;
        gload_lds16(kh + (size_t)j * 512 + cs * 8, &Ksh[cg * 64 * 8]);
    }
    #pragma unroll
    for (int it = 0; it < 6; ++it) {
        const int cg  = it * 4 + w;
        const int cid = cg * 64 + l;
        const int blk = cid / 384;
        const int rem = cid - blk * 384;
        const int prow = rem >> 1, hf = rem & 1;
        const int a = prow >> 2, bb = prow & 3;
        const int k = (a < 24) ? (8 * a + bb) : (8 * (a - 24) + 4 + bb);
        int j = j0 + k; if (j < 0) j = 0;
        gload_lds16(vh + (size_t)j * 512 + blk * 16 + hf * 8, &Vsh[cg * 64 * 8]);
    }

    bf16x8 qa[2];
    {
        const unsigned short* qrow = qh + (size_t)(i0 + 16 * w + lr) * 512;
        qa[0] = *(const bf16x8*)(qrow + lhi * 8);
        qa[1] = *(const bf16x8*)(qrow + 32 + lhi * 8);
    }
    __syncthreads();

    const int jcbase = w & ~1;
    f32x4 sacc[10];
    #pragma unroll
    for (int jc = 0; jc < 10; ++jc) sacc[jc] = (f32x4){0.f, 0.f, 0.f, 0.f};

    __builtin_amdgcn_s_setprio(1);
    #pragma unroll
    for (int kk = 0; kk < 2; ++kk) {
        const int ch = (kk * 4 + lhi) ^ (lr & 7);
        #pragma unroll
        for (int jc = 0; jc < 10; ++jc) {
            const int row = (jcbase + jc) * 16 + lr;
            bf16x8 kf = *(const bf16x8*)&Ksh[row * 64 + ch * 8];
            sacc[jc] = __builtin_amdgcn_mfma_f32_16x16x32_bf16(
                qa[kk], kf, sacc[jc], 0, 0, 0);
        }
    }
    __builtin_amdgcn_s_setprio(0);

    unsigned short* myP = &Psh[w * 3200];
    const int lo0 = 128 - i0;
    float lsum[4] = {0.f, 0.f, 0.f, 0.f};
    #pragma unroll
    for (int jc = 0; jc < 10; ++jc) {
        const int jcol = (jcbase + jc) * 16 + lr;
        #pragma unroll
        for (int rr = 0; rr < 4; ++rr) {
            const int iloc = 16 * w + 4 * lhi + rr;
            const bool ok = (jcol >= iloc) && (jcol <= iloc + ATTN_) && (jcol >= lo0);
            const float p = ok ? __expf(fminf(sacc[jc][rr] * scale, 80.f)) : 0.f;
            lsum[rr] += p;
            myP[(4 * lhi + rr) * 200 + jcol] = f2bf(p);
        }
    }
    #pragma unroll
    for (int rr = 0; rr < 4; ++rr) {
        float s = lsum[rr];
        s += __shfl_xor(s, 1, 16);
        s += __shfl_xor(s, 2, 16);
        s += __shfl_xor(s, 4, 16);
        s += __shfl_xor(s, 8, 16);
        lsum[rr] = s;
    }

    const int kcbase = w >> 1;
    f32x4 oacc[4];
    #pragma unroll
    for (int fn = 0; fn < 4; ++fn) oacc[fn] = (f32x4){0.f, 0.f, 0.f, 0.f};
    const unsigned vbase = lds_addr(&Vsh[0]) + (unsigned)(l * 8);

    for (int kc5 = 0; kc5 < 5; ++kc5) {
        const int kc = kcbase + kc5;
        bf16x8 pa = *(const bf16x8*)&myP[lr * 200 + kc * 32 + lhi * 8];
        u32x2 vlo[4], vhi[4];
        #pragma unroll
        for (int fn = 0; fn < 4; ++fn) {
            const unsigned addr = vbase + (unsigned)((fn * 3072 + kc * 256) * 2);
            asm volatile("ds_read_b64_tr_b16 %0, %1" : "=v"(vlo[fn]) : "v"(addr));
            asm volatile("ds_read_b64_tr_b16 %0, %1 offset:3072"
                         : "=v"(vhi[fn]) : "v"(addr));
        }
        asm volatile("s_waitcnt lgkmcnt(0)" ::: "memory");
        __builtin_amdgcn_sched_barrier(0);
        __builtin_amdgcn_s_setprio(1);
        #pragma unroll
        for (int fn = 0; fn < 4; ++fn) {
            union { u32x2 h[2]; bf16x8 v; } u;
            u.h[0] = vlo[fn]; u.h[1] = vhi[fn];
            oacc[fn] = __builtin_amdgcn_mfma_f32_16x16x32_bf16(
                pa, u.v, oacc[fn], 0, 0, 0);
        }
        __builtin_amdgcn_s_setprio(0);
    }

    float inv[4];
    #pragma unroll
    for (int rr = 0; rr < 4; ++rr) inv[rr] = 1.f / lsum[rr];
    #pragma unroll
    for (int fn = 0; fn < 4; ++fn)
        #pragma unroll
        for (int rr = 0; rr < 4; ++rr) {
            const int row = i0 + 16 * w + 4 * lhi + rr;
            oh[(size_t)row * 512 + fn * 16 + lr] = f2bf(oacc[fn][rr] * inv[rr]);
        }
}

// ---------------------------------------------------------------------------
extern "C" void kernel_launch(void* const* d_in, const int* in_sizes, int n_in,
                              void* d_out, int out_size, void* d_ws, size_t ws_size,
                              hipStream_t stream)
{
    const float* query = (const float*)d_in[0];
    const float* key   = (const float*)d_in[1];
    const float* value = (const float*)d_in[2];
    const float* W_q   = (const float*)d_in[3];
    const float* b_q   = (const float*)d_in[4];
    const float* W_k   = (const float*)d_in[5];
    const float* b_k   = (const float*)d_in[6];
    const float* W_v   = (const float*)d_in[7];
    const float* b_v   = (const float*)d_in[8];
    const float* W_o   = (const float*)d_in[9];
    const float* b_o   = (const float*)d_in[10];
    float* out = (float*)d_out;

    const size_t NX = (size_t)M_ * 512;
    const size_t NW = 512 * 512;
    unsigned short* wqb = (unsigned short*)d_ws;
    unsigned short* wkb = wqb + NW;
    unsigned short* wvb = wkb + NW;
    unsigned short* wob = wvb + NW;
    unsigned short* qp  = wob + NW;
    unsigned short* kp  = qp + NX;
    unsigned short* vp  = kp + NX;
    unsigned short* ap  = vp + NX;

    const int NW8 = (int)(NW / 8);

    CvtA a;
    a.c[0] = { W_q, wqb, NW8 };
    a.c[1] = { W_k, wkb, NW8 };
    a.c[2] = { W_v, wvb, NW8 };
    a.c[3] = { W_o, wob, NW8 };
    cvt_multi<<<dim3(32, 4), 256, 0, stream>>>(a);

    GArgs qa;
    qa.A[0] = query; qa.A[1] = key; qa.A[2] = value;
    qa.Wt[0] = wqb;  qa.Wt[1] = wkb; qa.Wt[2] = wvb;
    qa.bias[0] = b_q; qa.bias[1] = b_k; qa.bias[2] = b_v;
    qa.C[0] = qp; qa.C[1] = kp; qa.C[2] = vp;
    gemm256<true, true><<<192, 512, 0, stream>>>(qa);   // fused-M: 96 mt x 2 nt

    attn_mfma<<<dim3(32, 8, 4), 256, 0, stream>>>(qp, kp, vp, ap);

    GArgs oa;
    oa.A[0] = ap; oa.A[1] = ap; oa.A[2] = ap;
    oa.Wt[0] = wob; oa.Wt[1] = wob; oa.Wt[2] = wob;
    oa.bias[0] = b_o; oa.bias[1] = b_o; oa.bias[2] = b_o;
    oa.C[0] = out; oa.C[1] = out; oa.C[2] = out;
    gemm256<false, false><<<64, 512, 0, stream>>>(oa);  // 32 mt x 2 nt
}